// Round 1
// baseline (544.820 us; speedup 1.0000x reference)
//
#include <hip/hip_runtime.h>
#include <hip/hip_bf16.h>

#define NDIM  3
#define NCOL  2000
#define RANK  64
#define K1    64
#define NSAMP 8192
constexpr float LAMBD = 0.01f;

__global__ void zero_out_kernel(float* out) {
    if (threadIdx.x == 0 && blockIdx.x == 0) out[0] = 0.0f;
}

// One block per sample n. 256 threads.
// Thread t: r-quad = 4*(t&15), k-group = t>>4.
// eps float4 flat index within this n's [K1][RANK] chunk = iter*256 + t  (coalesced).
__global__ __launch_bounds__(256) void ssvi_loss_kernel(
    const int*   __restrict__ entries,  // [NSAMP, 3]
    const float* __restrict__ ys,       // [NSAMP]
    const float* __restrict__ eps,      // [3, NSAMP, K1, RANK]
    const float* __restrict__ means,    // [3, NCOL, RANK]
    const float* __restrict__ chols,    // [3, NCOL, RANK]
    float*       __restrict__ out)
{
    const int n = blockIdx.x;
    const int t = threadIdx.x;

    __shared__ float sm[NDIM][RANK];
    __shared__ float sl[NDIM][RANK];   // Lsq = L^2
    __shared__ float wsum[4];

    // Gather means/chols rows + per-(d,r) KL term. 192 threads cover 3*64.
    float kl_part = 0.0f;
    if (t < NDIM * RANK) {
        const int d = t >> 6;
        const int r = t & 63;
        const int col = entries[n * NDIM + d];          // broadcast via cache
        const float mv = means[((size_t)d * NCOL + col) * RANK + r];
        const float lv = chols[((size_t)d * NCOL + col) * RANK + r];
        const float ls = lv * lv;                        // S = L^2
        sm[d][r] = mv;
        sl[d][r] = ls;
        // kl_term = 1 + log(S^2) - m^2 - S^2
        kl_part = 1.0f + 2.0f * __logf(ls) - mv * mv - ls * ls;
    }
    __syncthreads();

    const int r4 = (t & 15) * 4;
    float m0[4], m1[4], m2[4], l0[4], l1[4], l2[4];
    #pragma unroll
    for (int j = 0; j < 4; ++j) {
        m0[j] = sm[0][r4 + j];  l0[j] = sl[0][r4 + j];
        m1[j] = sm[1][r4 + j];  l1[j] = sl[1][r4 + j];
        m2[j] = sm[2][r4 + j];  l2[j] = sl[2][r4 + j];
    }
    const float yn = ys[n];

    const size_t chunk = (size_t)K1 * RANK;             // 4096 floats per (d,n)
    const float4* e0p = (const float4*)(eps + (0 * (size_t)NSAMP + n) * chunk);
    const float4* e1p = (const float4*)(eps + (1 * (size_t)NSAMP + n) * chunk);
    const float4* e2p = (const float4*)(eps + (2 * (size_t)NSAMP + n) * chunk);

    float pdf_acc = 0.0f;
    #pragma unroll
    for (int iter = 0; iter < 4; ++iter) {
        const int idx = iter * 256 + t;
        const float4 e0 = e0p[idx];
        const float4 e1 = e1p[idx];
        const float4 e2 = e2p[idx];

        float part;
        {
            const float f0 = (m0[0] + e0.x * l0[0]) * (m1[0] + e1.x * l1[0]) * (m2[0] + e2.x * l2[0]);
            const float f1 = (m0[1] + e0.y * l0[1]) * (m1[1] + e1.y * l1[1]) * (m2[1] + e2.y * l2[1]);
            const float f2 = (m0[2] + e0.z * l0[2]) * (m1[2] + e1.z * l1[2]) * (m2[2] + e2.z * l2[2]);
            const float f3 = (m0[3] + e0.w * l0[3]) * (m1[3] + e1.w * l1[3]) * (m2[3] + e2.w * l2[3]);
            part = (f0 + f1) + (f2 + f3);
        }
        // Reduce over the 16 lanes sharing this k (xor within lane group).
        #pragma unroll
        for (int off = 8; off > 0; off >>= 1)
            part += __shfl_xor(part, off, 64);

        if ((t & 15) == 0) {
            const float diff = part - yn;
            pdf_acc += diff * diff;
        }
    }

    // Per-thread contribution to the final loss.
    float val = pdf_acc * (0.5f / (float)K1) + kl_part * (0.5f * LAMBD);

    // Wave (64) reduce, then block reduce via LDS, then one atomic per block.
    #pragma unroll
    for (int off = 32; off > 0; off >>= 1)
        val += __shfl_xor(val, off, 64);
    if ((t & 63) == 0) wsum[t >> 6] = val;
    __syncthreads();
    if (t == 0) atomicAdd(out, (wsum[0] + wsum[1]) + (wsum[2] + wsum[3]));
}

extern "C" void kernel_launch(void* const* d_in, const int* in_sizes, int n_in,
                              void* d_out, int out_size, void* d_ws, size_t ws_size,
                              hipStream_t stream) {
    const int*   entries = (const int*)  d_in[0];
    const float* ys      = (const float*)d_in[1];
    const float* eps     = (const float*)d_in[2];
    const float* means   = (const float*)d_in[3];
    const float* chols   = (const float*)d_in[4];
    float* out = (float*)d_out;

    zero_out_kernel<<<1, 64, 0, stream>>>(out);
    ssvi_loss_kernel<<<NSAMP, 256, 0, stream>>>(entries, ys, eps, means, chols, out);
}